// Round 3
// baseline (488.331 us; speedup 1.0000x reference)
//
#include <hip/hip_runtime.h>

typedef __bf16 bf16;
typedef __bf16 bf16x8 __attribute__((ext_vector_type(8)));
typedef float f32x16 __attribute__((ext_vector_type(16)));

#define B_ROWS 16384
#define N_DIM  4096
#define K_DIM  128

// ---------------------------------------------------------------------------
// Kernel 1: transpose V (4096x128 f32) -> Ut (128x4096 bf16), fused with
// per-column partial sums (for s = V.sum(0)).
// ---------------------------------------------------------------------------
__global__ __launch_bounds__(256) void prep_kernel(const float* __restrict__ V,
                                                   float* __restrict__ spart,
                                                   bf16* __restrict__ Ut) {
    __shared__ bf16 tile[128 * 136];
    __shared__ float sp[256];
    const int t = threadIdx.x;
    const int jbase = blockIdx.x * 128;
    const int c  = t & 127;
    const int j0 = t >> 7;

    float sacc = 0.f;
#pragma unroll 8
    for (int i = 0; i < 64; ++i) {
        int j = j0 + 2 * i;
        float v = V[(size_t)(jbase + j) * K_DIM + c];
        sacc += v;
        tile[c * 136 + j] = (bf16)v;
    }
    sp[t] = sacc;
    __syncthreads();
    if (t < 128) spart[blockIdx.x * 128 + t] = sp[t] + sp[t + 128];

    const int col = t >> 1, half = t & 1;
#pragma unroll
    for (int i = 0; i < 4; ++i) {
        uint4 d = *(const uint4*)&tile[col * 136 + half * 64 + i * 16];
        *(uint4*)&Ut[(size_t)col * N_DIM + jbase + half * 64 + i * 16] = d;
    }
}

// ---------------------------------------------------------------------------
// Kernel 2: snorm = ||V.sum(0)||^2
// ---------------------------------------------------------------------------
__global__ __launch_bounds__(128) void finalize_s(const float* __restrict__ spart,
                                                  float* __restrict__ snorm_out) {
    const int t = threadIdx.x;
    float s = 0.f;
#pragma unroll
    for (int b = 0; b < 32; ++b) s += spart[b * 128 + t];
    float sq = s * s;
#pragma unroll
    for (int m = 32; m >= 1; m >>= 1) sq += __shfl_down(sq, m, 64);
    __shared__ float red[2];
    if ((t & 63) == 0) red[t >> 6] = sq;
    __syncthreads();
    if (t == 0) snorm_out[0] = red[0] + red[1];
}

// ---------------------------------------------------------------------------
// Kernel 3: main — BARRIER-FREE. 512 blocks x 256 threads (4 waves, 2 blk/CU).
// Wave w: rows r0..r0+31 (shared across waves, L1 absorbs the 4x re-read),
// cols w*32..w*32+31. MFMA operands loaded DIRECTLY from global per lane in
// fragment order (same lane->element map the R1 LDS reads used):
//   A: lane(l31,h) <- x[r0+l31][kb+ks+h*8 ..+7]  (f32, cvt to bf16 in-reg)
//   B: lane(l31,h) <- Ut[w*32+l31][kb+ks+h*8 ..+7]
// No __syncthreads in the K-loop -> no vmcnt(0) drains; compiler pipelines
// with fine-grained vmcnt. Wave 0 also accumulates exact fp32 xsum & x.W
// (its lanes cover each (row,k) exactly once).
// ---------------------------------------------------------------------------
__global__ __launch_bounds__(256, 2) void fm_main(const float* __restrict__ x,
                                                  const float* __restrict__ W,
                                                  const float* __restrict__ bptr,
                                                  const bf16* __restrict__ Ut,
                                                  const float* __restrict__ snorm_ptr,
                                                  float* __restrict__ out) {
    __shared__ float rowsq[4 * 32];
    __shared__ float redx[32];
    __shared__ float redw[32];

    const int t    = threadIdx.x;
    const int wave = t >> 6;
    const int lane = t & 63;
    const int l31  = lane & 31;
    const int h    = lane >> 5;
    const int r0   = blockIdx.x * 32;

    f32x16 acc;
#pragma unroll
    for (int i = 0; i < 16; ++i) acc[i] = 0.f;

    float xs_acc = 0.f, xw_acc = 0.f;

    const float* xp = x + (size_t)(r0 + l31) * N_DIM + h * 8;
    const bf16*  up = Ut + (size_t)(wave * 32 + l31) * N_DIM + h * 8;
    const float* wp = W + h * 8;

    for (int kb = 0; kb < N_DIM; kb += 64) {
        float4 xa0[4], xa1[4];
        bf16x8 bfr[4];
#pragma unroll
        for (int j = 0; j < 4; ++j) {
            xa0[j] = *(const float4*)(xp + kb + j * 16);
            xa1[j] = *(const float4*)(xp + kb + j * 16 + 4);
            bfr[j] = *(const bf16x8*)(up + kb + j * 16);
        }

        if (wave == 0) {   // wave-uniform branch; exact fp32 side terms
#pragma unroll
            for (int j = 0; j < 4; ++j) {
                float4 w0 = *(const float4*)(wp + kb + j * 16);
                float4 w1 = *(const float4*)(wp + kb + j * 16 + 4);
                xs_acc += (xa0[j].x + xa0[j].y + xa0[j].z + xa0[j].w)
                        + (xa1[j].x + xa1[j].y + xa1[j].z + xa1[j].w);
                xw_acc += xa0[j].x * w0.x + xa0[j].y * w0.y + xa0[j].z * w0.z + xa0[j].w * w0.w
                        + xa1[j].x * w1.x + xa1[j].y * w1.y + xa1[j].z * w1.z + xa1[j].w * w1.w;
            }
        }

#pragma unroll
        for (int j = 0; j < 4; ++j) {
            bf16x8 af;
            af[0] = (bf16)xa0[j].x; af[1] = (bf16)xa0[j].y;
            af[2] = (bf16)xa0[j].z; af[3] = (bf16)xa0[j].w;
            af[4] = (bf16)xa1[j].x; af[5] = (bf16)xa1[j].y;
            af[6] = (bf16)xa1[j].z; af[7] = (bf16)xa1[j].w;
            acc = __builtin_amdgcn_mfma_f32_32x32x16_bf16(af, bfr[j], acc, 0, 0, 0);
        }
    }

    // ---- epilogue ----
    // per-row sum of squares over this wave's 32 cols.
    // C/D layout: col = lane&31, row = (reg&3) + 8*(reg>>2) + 4*(lane>>5)
#pragma unroll
    for (int r = 0; r < 16; ++r) {
        float s = acc[r] * acc[r];
        s += __shfl_xor(s, 1);
        s += __shfl_xor(s, 2);
        s += __shfl_xor(s, 4);
        s += __shfl_xor(s, 8);
        s += __shfl_xor(s, 16);
        if (l31 == 0) rowsq[wave * 32 + ((r & 3) + 8 * (r >> 2) + 4 * h)] = s;
    }

    if (wave == 0) {
        xs_acc += __shfl_xor(xs_acc, 32);   // combine h halves -> full row sums
        xw_acc += __shfl_xor(xw_acc, 32);
        if (lane < 32) { redx[l31] = xs_acc; redw[l31] = xw_acc; }
    }
    __syncthreads();

    if (t < 32) {
        float sq = rowsq[t] + rowsq[32 + t] + rowsq[64 + t] + rowsq[96 + t];
        float xsum = redx[t];
        out[r0 + t] = bptr[0] + redw[t] + 0.5f * sq - 0.5f * xsum * xsum * snorm_ptr[0];
    }
}

// ---------------------------------------------------------------------------
extern "C" void kernel_launch(void* const* d_in, const int* in_sizes, int n_in,
                              void* d_out, int out_size, void* d_ws, size_t ws_size,
                              hipStream_t stream) {
    const float* x  = (const float*)d_in[0];
    const float* W  = (const float*)d_in[1];
    const float* bp = (const float*)d_in[2];
    const float* V  = (const float*)d_in[3];
    float* out = (float*)d_out;

    char* ws = (char*)d_ws;
    float* snorm = (float*)ws;                 // 4 B
    float* spart = (float*)(ws + 1024);        // 16 KB
    bf16*  Ut    = (bf16*)(ws + 32768);        // 1 MB

    hipLaunchKernelGGL(prep_kernel, dim3(32), dim3(256), 0, stream, V, spart, Ut);
    hipLaunchKernelGGL(finalize_s, dim3(1), dim3(128), 0, stream, spart, snorm);
    hipLaunchKernelGGL(fm_main, dim3(512), dim3(256), 0, stream, x, W, bp, Ut, snorm, out);
}

// Round 4
// 398.566 us; speedup vs baseline: 1.2252x; 1.2252x over previous
//
#include <hip/hip_runtime.h>

typedef __bf16 bf16;
typedef __bf16 bf16x4 __attribute__((ext_vector_type(4)));
typedef __bf16 bf16x8 __attribute__((ext_vector_type(8)));
typedef float f32x4 __attribute__((ext_vector_type(4)));

#define N_DIM 4096
#define K_DIM 128

// ---------------------------------------------------------------------------
// uf_prep: V (4096x128 f32) -> Uf in MFMA-B fragment order (bf16).
// Fragment unit = (ct, kb): 64 lanes x 8 bf16, element (col = ct*16 + (lane&15),
// k = kb*32 + (lane>>4)*8 + j). Stored so lane i's 16B sits at +i*16 ->
// fm_main's B load is one fully coalesced dwordx4 per wave.
// 256 blocks x 256 threads; one thread = one lane-fragment.
// ---------------------------------------------------------------------------
__global__ __launch_bounds__(256) void uf_prep(const float* __restrict__ V,
                                               bf16* __restrict__ Uf) {
    const int g    = blockIdx.x * 256 + threadIdx.x;
    const int lane = g & 63;
    const int task = g >> 6;            // 0..1023 = ct*128 + kb
    const int col  = (task >> 7) * 16 + (lane & 15);
    const int k0   = (task & 127) * 32 + (lane >> 4) * 8;
    bf16x8 v;
#pragma unroll
    for (int j = 0; j < 8; ++j)
        v[j] = (bf16)V[(size_t)(k0 + j) * K_DIM + col];
    *(bf16x8*)(Uf + (size_t)task * 512 + lane * 8) = v;
}

// ---------------------------------------------------------------------------
// colsum_part + finalize_s: snorm = ||V.sum(0)||^2 (exact fp32)
// ---------------------------------------------------------------------------
__global__ __launch_bounds__(256) void colsum_part(const float* __restrict__ V,
                                                   float* __restrict__ spart) {
    __shared__ float sp[256];
    const int t = threadIdx.x;
    const int jbase = blockIdx.x * 128;
    const int c = t & 127, j0 = t >> 7;
    float s = 0.f;
#pragma unroll 8
    for (int i = 0; i < 64; ++i)
        s += V[(size_t)(jbase + j0 + 2 * i) * K_DIM + c];
    sp[t] = s;
    __syncthreads();
    if (t < 128) spart[blockIdx.x * 128 + t] = sp[t] + sp[t + 128];
}

__global__ __launch_bounds__(128) void finalize_s(const float* __restrict__ spart,
                                                  float* __restrict__ snorm_out) {
    const int t = threadIdx.x;
    float s = 0.f;
#pragma unroll
    for (int b = 0; b < 32; ++b) s += spart[b * 128 + t];
    float sq = s * s;
#pragma unroll
    for (int m = 32; m >= 1; m >>= 1) sq += __shfl_down(sq, m, 64);
    __shared__ float red[2];
    if ((t & 63) == 0) red[t >> 6] = sq;
    __syncthreads();
    if (t == 0) snorm_out[0] = red[0] + red[1];
}

// ---------------------------------------------------------------------------
// fm_main: BM=16 rows/block -> 1024 blocks (4/CU), 256 threads = 4 waves.
// Wave w: col-tiles ct0=2w, ct1=2w+1 (16 cols each), mfma_f32_16x16x32_bf16.
// K-loop (64 iters of BK=64): x staged regs->LDS (coalesced loads; barrier
// only needs lgkm drain since LDS written from registers); B-fragments loaded
// straight from L2-resident fragment-ordered Uf (coalesced 1KB/wave);
// exact fp32 xsum & x.W accumulated per-thread on the staging registers.
// A-frag layout (verified m118/m120): A[m=lane&15][k=(lane>>4)*8+j].
// C/D layout  (verified m89/m91):    col=lane&15, row=(lane>>4)*4+reg.
// ---------------------------------------------------------------------------
__global__ __launch_bounds__(256, 4) void fm_main(const float* __restrict__ x,
                                                  const float* __restrict__ W,
                                                  const float* __restrict__ bptr,
                                                  const bf16* __restrict__ Uf,
                                                  const float* __restrict__ snorm_ptr,
                                                  float* __restrict__ out) {
    __shared__ bf16  xs[2][16 * 72];       // double-buffered x tile, +8 pad
    __shared__ float redx[256], redw[256];
    __shared__ float rowsq[64];

    const int t    = threadIdx.x;
    const int wave = t >> 6;
    const int lane = t & 63;
    const int l15  = lane & 15;
    const int quad = lane >> 4;
    const int r0   = blockIdx.x * 16;

    const int srow = t >> 4;               // 0..15 x row
    const int sch  = t & 15;               // 0..15 chunk of 4 floats

    f32x4 acc0, acc1;
#pragma unroll
    for (int i = 0; i < 4; ++i) { acc0[i] = 0.f; acc1[i] = 0.f; }

    float xs_acc = 0.f, xw_acc = 0.f;
    const float* xrow = x + (size_t)(r0 + srow) * N_DIM + sch * 4;
    const float* wrow = W + sch * 4;
    // B fragment base: lane's 8 bf16 of fragment (ct, kb) at Uf + (ct*128+kb)*512 + lane*8
    const bf16* ub0 = Uf + (size_t)(2 * wave) * 128 * 512 + lane * 8;
    const bf16* ub1 = ub0 + 128 * 512;

    // prologue: tile 0 into regs
    float4 a  = *(const float4*)(xrow);
    float4 wv = *(const float4*)(wrow);

    for (int it = 0; it < 64; ++it) {
        const int b = it & 1;
        const int knext = (it < 63) ? (it + 1) * 64 : 0;   // clamped harmless reload

        // ---- stage tile it: regs -> LDS (bf16) ----
        bf16x4 xb;
        xb[0] = (bf16)a.x; xb[1] = (bf16)a.y; xb[2] = (bf16)a.z; xb[3] = (bf16)a.w;
        *(bf16x4*)&xs[b][srow * 72 + sch * 4] = xb;

        __syncthreads();   // lgkm drain only (LDS written from regs, not DMA)

        // ---- prefetch tile it+1 (full iteration of slack before use) ----
        float4 na  = *(const float4*)(xrow + knext);
        float4 nwv = *(const float4*)(wrow + knext);

        // ---- B fragments for this iter (coalesced, L2-resident) ----
        const int kb = 2 * it;
        bf16x8 b0a = *(const bf16x8*)(ub0 + (size_t)kb * 512);
        bf16x8 b0b = *(const bf16x8*)(ub0 + (size_t)(kb + 1) * 512);
        bf16x8 b1a = *(const bf16x8*)(ub1 + (size_t)kb * 512);
        bf16x8 b1b = *(const bf16x8*)(ub1 + (size_t)(kb + 1) * 512);

        // ---- exact fp32 side terms on tile-it regs ----
        xs_acc += a.x + a.y + a.z + a.w;
        xw_acc += a.x * wv.x + a.y * wv.y + a.z * wv.z + a.w * wv.w;

        // ---- A fragments from LDS, 2 k-steps x 2 col-tiles ----
        bf16x8 af0 = *(const bf16x8*)&xs[b][l15 * 72 + quad * 8];
        bf16x8 af1 = *(const bf16x8*)&xs[b][l15 * 72 + 32 + quad * 8];
        acc0 = __builtin_amdgcn_mfma_f32_16x16x32_bf16(af0, b0a, acc0, 0, 0, 0);
        acc0 = __builtin_amdgcn_mfma_f32_16x16x32_bf16(af1, b0b, acc0, 0, 0, 0);
        acc1 = __builtin_amdgcn_mfma_f32_16x16x32_bf16(af0, b1a, acc1, 0, 0, 0);
        acc1 = __builtin_amdgcn_mfma_f32_16x16x32_bf16(af1, b1b, acc1, 0, 0, 0);

        a = na; wv = nwv;
    }

    // ---- epilogue ----
    // lane (l15, quad) reg r holds xv[row = quad*4 + r][col = ct*16 + l15]
#pragma unroll
    for (int r = 0; r < 4; ++r) {
        float s = acc0[r] * acc0[r] + acc1[r] * acc1[r];
        s += __shfl_xor(s, 1);
        s += __shfl_xor(s, 2);
        s += __shfl_xor(s, 4);
        s += __shfl_xor(s, 8);
        if (l15 == 0) rowsq[wave * 16 + quad * 4 + r] = s;
    }
    redx[t] = xs_acc;
    redw[t] = xw_acc;
    __syncthreads();

    if (t < 16) {
        float sq = rowsq[t] + rowsq[16 + t] + rowsq[32 + t] + rowsq[48 + t];
        float xsum = 0.f, xw = 0.f;
#pragma unroll
        for (int i = 0; i < 16; ++i) { xsum += redx[t * 16 + i]; xw += redw[t * 16 + i]; }
        out[r0 + t] = bptr[0] + xw + 0.5f * sq - 0.5f * xsum * xsum * snorm_ptr[0];
    }
}

// ---------------------------------------------------------------------------
extern "C" void kernel_launch(void* const* d_in, const int* in_sizes, int n_in,
                              void* d_out, int out_size, void* d_ws, size_t ws_size,
                              hipStream_t stream) {
    const float* x  = (const float*)d_in[0];
    const float* W  = (const float*)d_in[1];
    const float* bp = (const float*)d_in[2];
    const float* V  = (const float*)d_in[3];
    float* out = (float*)d_out;

    char* ws = (char*)d_ws;
    float* snorm = (float*)ws;                 // 4 B
    float* spart = (float*)(ws + 1024);        // 16 KB
    bf16*  Uf    = (bf16*)(ws + 32768);        // 1 MB fragment-ordered

    hipLaunchKernelGGL(uf_prep,     dim3(256), dim3(256), 0, stream, V, Uf);
    hipLaunchKernelGGL(colsum_part, dim3(32),  dim3(256), 0, stream, V, spart);
    hipLaunchKernelGGL(finalize_s,  dim3(1),   dim3(128), 0, stream, spart, snorm);
    hipLaunchKernelGGL(fm_main,     dim3(1024), dim3(256), 0, stream, x, W, bp, Uf, snorm, out);
}